// Round 8
// baseline (1210.305 us; speedup 1.0000x reference)
//
#include <hip/hip_runtime.h>
#include <hip/hip_bf16.h>

#define BSZ 32
#define TT 50
#define NN 192
#define HH 32
#define NSTEP (TT - 1)
#define NODES_PER_BLK 8
#define NBLK (BSZ * NN / NODES_PER_BLK)   // 768

typedef __attribute__((ext_vector_type(8))) short bf16x8;
typedef __attribute__((ext_vector_type(8))) _Float16 f16x8;
typedef __attribute__((ext_vector_type(2))) _Float16 f16x2;
typedef __attribute__((ext_vector_type(4))) float f32x4;

#define MFMA16(A, B, C) __builtin_amdgcn_mfma_f32_16x16x32_bf16((A), (B), (C), 0, 0, 0)
#define MFMAH(A, B, C)  __builtin_amdgcn_mfma_f32_16x16x32_f16((A), (B), (C), 0, 0, 0)

__device__ __forceinline__ float relu(float x) { return x > 0.0f ? x : 0.0f; }

// degree-9 odd polynomial tanh on [-1.2, 1.2], abs err <~4e-5 in-range (f32).
__device__ __forceinline__ float tanh9(float x) {
    x = fminf(1.2f, fmaxf(-1.2f, x));
    float u = x * x;
    float h = __builtin_fmaf(u, 0.0090878f, -0.0447732f);
    h = __builtin_fmaf(u, h, 0.1302534f);
    h = __builtin_fmaf(u, h, -0.3329694f);
    h = __builtin_fmaf(u, h, 1.0000104f);
    return x * h;
}
__device__ __forceinline__ float sigmoid9(float x) {
    return __builtin_fmaf(0.5f, tanh9(0.5f * x), 0.5f);
}

// packed-f16 tanh poly via native ext-vector ops (lowers to v_pk_* on gfx950)
__device__ __forceinline__ f16x2 splat2(float v) {
    f16x2 r;
    r[0] = (_Float16)v; r[1] = (_Float16)v;
    return r;
}
__device__ __forceinline__ f16x2 tanh9h2(f16x2 x) {
    x = __builtin_elementwise_min(__builtin_elementwise_max(x, splat2(-1.2f)), splat2(1.2f));
    f16x2 u = x * x;
    f16x2 h = __builtin_elementwise_fma(u, splat2(0.0090878f), splat2(-0.0447732f));
    h = __builtin_elementwise_fma(u, h, splat2(0.1302534f));
    h = __builtin_elementwise_fma(u, h, splat2(-0.3329694f));
    h = __builtin_elementwise_fma(u, h, splat2(1.0000104f));
    return x * h;
}

union U8 { bf16x8 v; __hip_bfloat162 p[4]; };
union UH { f16x8 v; f16x2 p[4]; };

__device__ __forceinline__ void ld8(const float* p, float* x) {
    const float4* q = (const float4*)p;
    float4 a = q[0], c = q[1];
    x[0] = a.x; x[1] = a.y; x[2] = a.z; x[3] = a.w;
    x[4] = c.x; x[5] = c.y; x[6] = c.z; x[7] = c.w;
}
__device__ __forceinline__ bf16x8 pack8(const float* x) {
    U8 u;
#pragma unroll
    for (int i = 0; i < 4; ++i)
        u.p[i] = __float22bfloat162_rn(make_float2(x[2 * i], x[2 * i + 1]));
    return u.v;
}
__device__ __forceinline__ f16x8 packh8(const float* x) {
    UH u;
#pragma unroll
    for (int i = 0; i < 8; ++i) u.v[i] = (_Float16)x[i];
    return u.v;
}
__device__ __forceinline__ void split8(const float* x, bf16x8& hi, bf16x8& lo) {
    U8 H, L;
#pragma unroll
    for (int i = 0; i < 4; ++i) {
        __hip_bfloat162 h = __float22bfloat162_rn(make_float2(x[2 * i], x[2 * i + 1]));
        float2 hf = __bfloat1622float2(h);
        H.p[i] = h;
        L.p[i] = __float22bfloat162_rn(make_float2(x[2 * i] - hf.x, x[2 * i + 1] - hf.y));
    }
    hi = H.v; lo = L.v;
}
__device__ __forceinline__ void loadB_hl(const float* Wrow, bf16x8& h, bf16x8& l) {
    float x[8];
    ld8(Wrow, x);
    split8(x, h, l);
}

// ---------------- per-step kernel: agg + gates + hn + send/recv ----------------
// 512 thr = 8 waves = 8 nodes. Phase A in packed f16 + f16 MFMA.
__global__ __launch_bounds__(512, 6) void k_step(
    const int* __restrict__ skill, const float* __restrict__ adj,
    const float* __restrict__ emb,
    const float* __restrict__ Wmsg1, const float* __restrict__ bmsg1,
    const float* __restrict__ Wmsg2, const float* __restrict__ bmsg2,
    const float* __restrict__ W_hr, const float* __restrict__ W_hi, const float* __restrict__ W_hh,
    const float* __restrict__ W_ir, const float* __restrict__ b_ir,
    const float* __restrict__ W_ii, const float* __restrict__ b_ii,
    const float* __restrict__ W_in, const float* __restrict__ b_in,
    const float* __restrict__ sbr, float* __restrict__ sbw,
    float* __restrict__ rbuf,
    const float* __restrict__ hprev, float* __restrict__ hcur, int t)
{
    __shared__ alignas(16) _Float16 spsh[NN][40];   // send_p[b] staged in f16 (15.4 KB)
    __shared__ alignas(16) float aggsh[16][36];
    __shared__ alignas(16) float hnsh[16][36];
    __shared__ float grsh[8][33], gish[8][33], gnsh[8][33], ggsh[8][33];

    const int tid = threadIdx.x;
    const int w = tid >> 6, lane = tid & 63;
    const int n16 = lane & 15, kg = lane >> 4, k8 = kg * 8;
    const int node0 = blockIdx.x * NODES_PER_BLK;
    const int b = node0 / NN;
    const int node = node0 + w;
    const int prod = w >> 1, hf = w & 1;
    const int rowb = hf * 16 + n16;

    // prefetch hprev early (used after 3 barriers)
    float hold = 0.f;
    if (tid < 256)
        hold = hprev[(size_t)(node0 + (tid >> 5)) * HH + (tid & 31)];

    // stage send_p[b] -> f16 LDS
    {
        const float* sb = sbr + (size_t)b * NN * HH;
        for (int i = tid; i < NN * HH / 8; i += 512) {   // 768 chunks of 8 floats
            float x[8];
            ld8(sb + i * 8, x);
            *(f16x8*)&spsh[i >> 2][(i & 3) * 8] = packh8(x);
        }
    }
    // rvp = f16(recv + b1)
    UH rv;
    {
        float xr[8], xc[8];
        ld8(rbuf + (size_t)node * HH + k8, xr);
        ld8(bmsg1 + k8, xc);
#pragma unroll
        for (int i = 0; i < 8; ++i) rv.v[i] = (_Float16)(xr[i] + xc[i]);
    }
    // phase-A B-frags: W2^T in f16
    f16x8 Bh0, Bh1;
    {
        float x[8];
        ld8(Wmsg2 + (size_t)n16 * HH + k8, x);
        Bh0 = packh8(x);
        ld8(Wmsg2 + (size_t)(16 + n16) * HH + k8, x);
        Bh1 = packh8(x);
    }
    const float bb2_0 = bmsg2[n16], bb2_1 = bmsg2[16 + n16];
    const float* ar = adj + (size_t)node * NN;

    // per-wave gate weight fragments (role = prod, half = hf) — bf16 hi/lo
    bf16x8 F0h{}, F0l{}, F1h{}, F1l{}, G0h{}, G0l{};
    float bias1 = 0.f;
    if (prod == 0) {            // R gate; later S (send)
        loadB_hl(W_hr + (size_t)rowb * HH + k8, F0h, F0l);
        loadB_hl(W_ir + (size_t)rowb * HH + k8, F1h, F1l);
        bias1 = b_ir[rowb];
        loadB_hl(Wmsg1 + (size_t)rowb * 2 * HH + k8, G0h, G0l);      // W_send
    } else if (prod == 1) {     // I gate; later V (recv)
        loadB_hl(W_hi + (size_t)rowb * HH + k8, F0h, F0l);
        loadB_hl(W_ii + (size_t)rowb * HH + k8, F1h, F1l);
        bias1 = b_ii[rowb];
        loadB_hl(Wmsg1 + (size_t)rowb * 2 * HH + HH + k8, G0h, G0l); // W_recv
    } else if (prod == 2) {     // N gate
        loadB_hl(W_in + (size_t)rowb * HH + k8, F0h, F0l);
        bias1 = b_in[rowb];
    } else {                    // G = agg @ W_hh^T
        loadB_hl(W_hh + (size_t)rowb * HH + k8, F0h, F0l);
    }
    __syncthreads();

    // ================= Phase A (packed-f16 msg1, f16 MFMA, f32 msg2-tanh) =======
    float acc0 = 0.f, acc1 = 0.f;
#pragma unroll 2
    for (int s0 = 0; s0 < NN; s0 += 16) {
        UH a, tv;
        a.v = *(const f16x8*)&spsh[s0 + n16][k8];
#pragma unroll
        for (int i = 0; i < 4; ++i)
            tv.p[i] = tanh9h2(a.p[i] + rv.p[i]);
        f32x4 c0 = MFMAH(tv.v, Bh0, ((f32x4){bb2_0, bb2_0, bb2_0, bb2_0}));
        f32x4 c1 = MFMAH(tv.v, Bh1, ((f32x4){bb2_1, bb2_1, bb2_1, bb2_1}));
        const float4 a2 = *(const float4*)(ar + s0 + 4 * kg);
        acc0 += a2.x * tanh9(c0[0]) + a2.y * tanh9(c0[1]) +
                a2.z * tanh9(c0[2]) + a2.w * tanh9(c0[3]);
        acc1 += a2.x * tanh9(c1[0]) + a2.y * tanh9(c1[1]) +
                a2.z * tanh9(c1[2]) + a2.w * tanh9(c1[3]);
    }
    acc0 += __shfl_xor(acc0, 16, 64); acc0 += __shfl_xor(acc0, 32, 64);
    acc1 += __shfl_xor(acc1, 16, 64); acc1 += __shfl_xor(acc1, 32, 64);
    if (kg == 0) {
        aggsh[w][n16]      = acc0 * (1.0f / (float)NN);
        aggsh[w][16 + n16] = acc1 * (1.0f / (float)NN);
    }
    __syncthreads();

    // ================= gates (8 waves: R0 R1 I0 I1 N0 N1 G0 G1) =================
    {
        bf16x8 Agh{}, Agl{}, Aih{}, Ail{};
        if (prod != 2) { float x[8]; ld8(&aggsh[n16][k8], x); split8(x, Agh, Agl); }
        if (prod <= 2) {
            float x[8];
            const float* er = emb + (size_t)skill[b * TT + t] * HH;
            ld8(er + k8, x); split8(x, Aih, Ail);
        }
        f32x4 C = {bias1, bias1, bias1, bias1};
        if (prod <= 1) {
            C = MFMA16(Agh, F0h, C); C = MFMA16(Agh, F0l, C); C = MFMA16(Agl, F0h, C);
            C = MFMA16(Aih, F1h, C); C = MFMA16(Aih, F1l, C); C = MFMA16(Ail, F1h, C);
        } else if (prod == 2) {
            C = MFMA16(Aih, F0h, C); C = MFMA16(Aih, F0l, C); C = MFMA16(Ail, F0h, C);
        } else {
            C = MFMA16(Agh, F0h, C); C = MFMA16(Agh, F0l, C); C = MFMA16(Agl, F0h, C);
        }
        float* dst = (prod == 0) ? &grsh[0][0] : (prod == 1) ? &gish[0][0]
                   : (prod == 2) ? &gnsh[0][0] : &ggsh[0][0];
        if (kg < 2) {
#pragma unroll
            for (int j = 0; j < 4; ++j) dst[(4 * kg + j) * 33 + rowb] = C[j];
        }
    }
    __syncthreads();

    // ================= elementwise: hn =================
    if (tid < 256) {
        const int row = tid >> 5, h = tid & 31;
        const float rg = sigmoid9(grsh[row][h]);
        const float ig = sigmoid9(gish[row][h]);
        const float ns = tanh9(gnsh[row][h] + rg * ggsh[row][h]);
        const float hn = (1.f - ig) * ns + ig * hold;
        hnsh[row][h] = hn;
        hcur[(size_t)(node0 + row) * HH + h] = hn;
    }
    __syncthreads();

    // ================= S/V projections (waves 0-3) =================
    if (w < 4) {
        const int p2 = w >> 1;      // 0:S 1:V
        bf16x8 Hh, Hl; float x[8];
        ld8(&hnsh[n16][k8], x); split8(x, Hh, Hl);
        f32x4 C = {0.f, 0.f, 0.f, 0.f};
        C = MFMA16(Hh, G0h, C); C = MFMA16(Hh, G0l, C); C = MFMA16(Hl, G0h, C);
        if (kg < 2) {
            float* dstg = (p2 == 0) ? sbw : rbuf;
#pragma unroll
            for (int j = 0; j < 4; ++j)
                dstg[(size_t)(node0 + 4 * kg + j) * HH + rowb] = C[j];
        }
    }
}

// ---------------- final head kernel: P1/P2/O for all node-steps ----------------
#define CHUNK 8
__global__ __launch_bounds__(512, 6) void k_head(
    const float* __restrict__ hist,    // [NSTEP][BSZ*NN][HH] (post-update hidden)
    const float* __restrict__ W_o1, const float* __restrict__ b_o1,
    const float* __restrict__ W_o2, const float* __restrict__ b_o2,
    const float* __restrict__ W_o3, const float* __restrict__ b_o3,
    float* __restrict__ out)
{
    __shared__ alignas(16) float tsh[8][16][36];
    const int tid = threadIdx.x;
    const int w = tid >> 6, lane = tid & 63;
    const int n16 = lane & 15, kg = lane >> 4, k8 = kg * 8;

    bf16x8 W1h[2], W1l[2], W2h[2], W2l[2], W3h[2], W3l[2];
    float bb1[2], bb2[2], bb3[2];
#pragma unroll
    for (int hf = 0; hf < 2; ++hf) {
        const int rowb = hf * 16 + n16;
        loadB_hl(W_o1 + (size_t)rowb * HH + k8, W1h[hf], W1l[hf]); bb1[hf] = b_o1[rowb];
        loadB_hl(W_o2 + (size_t)rowb * HH + k8, W2h[hf], W2l[hf]); bb2[hf] = b_o2[rowb];
        loadB_hl(W_o3 + (size_t)rowb * HH + k8, W3h[hf], W3l[hf]); bb3[hf] = b_o3[rowb];
    }

    const int wgid = blockIdx.x * 8 + w;
#pragma unroll 1
    for (int c = 0; c < CHUNK; ++c) {
        const int cid = wgid * CHUNK + c;
        const int rc = cid % 12;
        const int tt = (cid / 12) % NSTEP;
        const int bb = cid / (12 * NSTEP);

        const float* hrow = hist + ((size_t)tt * BSZ * NN + (size_t)bb * NN + rc * 16) * HH;
        float x[8];
        bf16x8 Ah, Al;
        ld8(hrow + (size_t)n16 * HH + k8, x);
        split8(x, Ah, Al);

        // layer 1
#pragma unroll
        for (int hf = 0; hf < 2; ++hf) {
            f32x4 C = {bb1[hf], bb1[hf], bb1[hf], bb1[hf]};
            C = MFMA16(Ah, W1h[hf], C); C = MFMA16(Ah, W1l[hf], C); C = MFMA16(Al, W1h[hf], C);
#pragma unroll
            for (int j = 0; j < 4; ++j) tsh[w][4 * kg + j][hf * 16 + n16] = relu(C[j]);
        }
        ld8(&tsh[w][n16][k8], x);
        split8(x, Ah, Al);

        // layer 2
#pragma unroll
        for (int hf = 0; hf < 2; ++hf) {
            f32x4 C = {bb2[hf], bb2[hf], bb2[hf], bb2[hf]};
            C = MFMA16(Ah, W2h[hf], C); C = MFMA16(Ah, W2l[hf], C); C = MFMA16(Al, W2h[hf], C);
#pragma unroll
            for (int j = 0; j < 4; ++j) tsh[w][4 * kg + j][hf * 16 + n16] = relu(C[j]);
        }
        ld8(&tsh[w][n16][k8], x);
        split8(x, Ah, Al);

        // layer 3 -> out[bb][tt][rc*16 + row][h]
        float* obase = out + (((size_t)bb * NSTEP + tt) * NN + rc * 16) * HH;
#pragma unroll
        for (int hf = 0; hf < 2; ++hf) {
            f32x4 C = {bb3[hf], bb3[hf], bb3[hf], bb3[hf]};
            C = MFMA16(Ah, W3h[hf], C); C = MFMA16(Ah, W3l[hf], C); C = MFMA16(Al, W3h[hf], C);
#pragma unroll
            for (int j = 0; j < 4; ++j)
                obase[(size_t)(4 * kg + j) * HH + hf * 16 + n16] = C[j];
        }
    }
}

extern "C" void kernel_launch(void* const* d_in, const int* in_sizes, int n_in,
                              void* d_out, int out_size, void* d_ws, size_t ws_size,
                              hipStream_t stream) {
    const int*   skill = (const int*)d_in[0];
    const float* adj   = (const float*)d_in[1];
    const float* emb   = (const float*)d_in[2];
    const float* Wmsg1 = (const float*)d_in[3];
    const float* bmsg1 = (const float*)d_in[4];
    const float* Wmsg2 = (const float*)d_in[5];
    const float* bmsg2 = (const float*)d_in[6];
    const float* W_hr  = (const float*)d_in[7];
    const float* W_hi  = (const float*)d_in[8];
    const float* W_hh  = (const float*)d_in[9];
    const float* W_ir  = (const float*)d_in[10];
    const float* b_ir  = (const float*)d_in[11];
    const float* W_ii  = (const float*)d_in[12];
    const float* b_ii  = (const float*)d_in[13];
    const float* W_in  = (const float*)d_in[14];
    const float* b_in  = (const float*)d_in[15];
    const float* W_o1  = (const float*)d_in[16];
    const float* b_o1  = (const float*)d_in[17];
    const float* W_o2  = (const float*)d_in[18];
    const float* b_o2  = (const float*)d_in[19];
    const float* W_o3  = (const float*)d_in[20];
    const float* b_o3  = (const float*)d_in[21];
    float* out = (float*)d_out;

    const size_t NH = (size_t)BSZ * NN * HH;     // 196608 floats
    float* ws = (float*)d_ws;
    float* sbuf0 = ws;                           // send ping (zeroed: read at t=0)
    float* rbuf  = ws + NH;                      // recv projections (zeroed)
    float* hzero = ws + 2 * NH;                  // hidden at t=-1 (zeroed)
    float* hist  = hzero;                        // slab u = t+1 at hist + u*NH
    float* sbuf1 = ws + (3 + NSTEP) * NH;        // send pong

    (void)hipMemsetAsync(d_ws, 0, 3 * NH * sizeof(float), stream);

    for (int t = 0; t < NSTEP; ++t) {
        const float* sbr = (t & 1) ? sbuf1 : sbuf0;
        float*       sbw = (t & 1) ? sbuf0 : sbuf1;
        const float* hprev = hist + (size_t)t * NH;
        float*       hcur  = hist + (size_t)(t + 1) * NH;
        k_step<<<NBLK, 512, 0, stream>>>(
            skill, adj, emb, Wmsg1, bmsg1, Wmsg2, bmsg2,
            W_hr, W_hi, W_hh, W_ir, b_ir, W_ii, b_ii, W_in, b_in,
            sbr, sbw, rbuf, hprev, hcur, t);
    }
    // head over all 49*6144 node-steps
    k_head<<<294, 512, 0, stream>>>(hist + NH, W_o1, b_o1, W_o2, b_o2, W_o3, b_o3, out);
}